// Round 2
// baseline (514.916 us; speedup 1.0000x reference)
//
#include <hip/hip_runtime.h>
#include <hip/hip_bf16.h>
#include <cstdint>

// CapsuleFC: B=16, N_IN=256, D_IN=128, N_OUT=128, D_OUT=64
// votes[b,n,m,d] = sum_a x[b,n,a] * W[n,a,m,d]        (W is 1 GiB fp32 -> HBM-bound)
// ncv[b,m,d]    = sum_n votes / N_OUT
// scores[b,n,m] = (1/8) * sum_d votes * ncv
// qk            = softmax_m(scores) * amean_b/(amean_b+1e-10)   (next_act const over m)
// out0[b,m,d]   = sum_n qk * act[b,n] * votes

#define BB 16
#define N_IN 256
#define D_IN 128
#define N_OUT 128
#define D_OUT 64
#define MD (N_OUT * D_OUT) /* 8192 */

// ---------------- Pass 1: votes (bf16) + ncv partial sums ----------------
// grid (32 md-chunks, 32 n-groups of 8), block 256.
__global__ __launch_bounds__(256) void pass1_votes(
    const float* __restrict__ x, const float* __restrict__ W,
    __hip_bfloat16* __restrict__ votes, float* __restrict__ ncv_acc)
{
    __shared__ float xs[BB * D_IN]; // 8 KB: x[:, n, :]
    const int t = threadIdx.x;
    const int chunk = blockIdx.x;   // 0..31 -> md columns
    const int ng = blockIdx.y;      // 0..31 -> 8 consecutive n
    const int j = chunk * 256 + t;  // md column 0..8191

    float ncvloc[BB];
#pragma unroll
    for (int b = 0; b < BB; ++b) ncvloc[b] = 0.f;

    for (int ni = 0; ni < 8; ++ni) {
        const int n = ng * 8 + ni;
        for (int r = t; r < BB * D_IN; r += 256) {
            const int b = r >> 7, a = r & 127;
            xs[r] = x[(size_t)b * (N_IN * D_IN) + (size_t)n * D_IN + a];
        }
        __syncthreads();

        float acc[BB];
#pragma unroll
        for (int b = 0; b < BB; ++b) acc[b] = 0.f;

        const float* Wn = W + (size_t)n * D_IN * MD + j;
#pragma unroll 4
        for (int a = 0; a < D_IN; ++a) {
            const float w = Wn[(size_t)a * MD];   // coalesced 1 KB/wave
#pragma unroll
            for (int b = 0; b < BB; ++b)
                acc[b] = fmaf(xs[b * D_IN + a], w, acc[b]);
        }

        const size_t vbase = (size_t)n * MD + j;
#pragma unroll
        for (int b = 0; b < BB; ++b) {
            votes[(size_t)b * ((size_t)N_IN * MD) + vbase] = __float2bfloat16(acc[b]);
            ncvloc[b] += acc[b];
        }
        __syncthreads();
    }
#pragma unroll
    for (int b = 0; b < BB; ++b)
        atomicAdd(&ncv_acc[b * MD + j], ncvloc[b]);
}

// ---------------- Pass 2: next_act + qk scale ----------------
__global__ __launch_bounds__(64) void pass2_act(
    const float* __restrict__ act, float* __restrict__ next_act_out,
    float* __restrict__ qk_scale)
{
    const int b = blockIdx.x;  // 16
    const int t = threadIdx.x; // 64
    float v = act[b * N_IN + t] + act[b * N_IN + 64 + t] +
              act[b * N_IN + 128 + t] + act[b * N_IN + 192 + t];
#pragma unroll
    for (int off = 32; off; off >>= 1) v += __shfl_down(v, off);
    v = __shfl(v, 0);
    const float amean = v * (1.f / 256.f);
    if (t == 0) qk_scale[b] = amean / (amean + 1e-10f);
    for (int m = t; m < N_OUT; m += 64) next_act_out[b * N_OUT + m] = amean;
}

// ---------------- Pass 3: scores -> softmax -> qk -> weighted reduce ----------------
// grid (16 b, 16 n-chunks of 16), block 256. thread t owns m=t>>1, d-half=t&1 (32 d's).
__global__ __launch_bounds__(256) void pass3_route(
    const __hip_bfloat16* __restrict__ votes, const float* __restrict__ ncv_acc,
    const float* __restrict__ act, const float* __restrict__ qk_scale,
    float* __restrict__ out0, float* __restrict__ qk_out)
{
    __shared__ float red[4];
    const int t = threadIdx.x;
    const int b = blockIdx.x;
    const int nc = blockIdx.y;
    const int m = t >> 1;
    const int half = t & 1;

    float nv[32], oacc[32];
    {
        const float4* np4 = reinterpret_cast<const float4*>(ncv_acc + (size_t)b * MD + t * 32);
#pragma unroll
        for (int q = 0; q < 8; ++q) {
            float4 f = np4[q];
            nv[4 * q + 0] = f.x; nv[4 * q + 1] = f.y;
            nv[4 * q + 2] = f.z; nv[4 * q + 3] = f.w;
        }
#pragma unroll
        for (int i = 0; i < 32; ++i) { nv[i] *= (1.f / (float)N_OUT); oacc[i] = 0.f; }
    }
    const float qs = qk_scale[b];

    for (int ni = 0; ni < 16; ++ni) {
        const int n = nc * 16 + ni;
        float vv[32];
        const uint4* vp = reinterpret_cast<const uint4*>(
            votes + (size_t)b * ((size_t)N_IN * MD) + (size_t)n * MD + t * 32);
#pragma unroll
        for (int q = 0; q < 4; ++q) {
            const uint4 u = vp[q];
            const uint32_t ww[4] = {u.x, u.y, u.z, u.w};
#pragma unroll
            for (int k = 0; k < 4; ++k) {
                vv[8 * q + 2 * k]     = __uint_as_float(ww[k] << 16);
                vv[8 * q + 2 * k + 1] = __uint_as_float(ww[k] & 0xffff0000u);
            }
        }
        // score for (b,n,m): dot over 64 d split across thread pair
        float sp = 0.f;
#pragma unroll
        for (int i = 0; i < 32; ++i) sp = fmaf(vv[i], nv[i], sp);
        sp += __shfl_xor(sp, 1);
        sp *= 0.125f; // 1/sqrt(D_OUT)

        // block max over m (duplicates harmless)
        float v = sp;
#pragma unroll
        for (int off = 32; off; off >>= 1) v = fmaxf(v, __shfl_xor(v, off));
        if ((t & 63) == 0) red[t >> 6] = v;
        __syncthreads();
        const float mx = fmaxf(fmaxf(red[0], red[1]), fmaxf(red[2], red[3]));
        __syncthreads();

        const float p = __expf(sp - mx);
        float s = p;
#pragma unroll
        for (int off = 32; off; off >>= 1) s += __shfl_xor(s, off);
        if ((t & 63) == 0) red[t >> 6] = s;
        __syncthreads();
        const float ssum = (red[0] + red[1] + red[2] + red[3]) * 0.5f; // each m counted twice
        __syncthreads();

        const float qk = (p / ssum) * qs;
        if (half == 0) qk_out[((size_t)(b * N_IN + n) << 7) + m] = qk;

        const float c = qk * act[b * N_IN + n];
#pragma unroll
        for (int i = 0; i < 32; ++i) oacc[i] = fmaf(c, vv[i], oacc[i]);
    }

    float* o = out0 + (size_t)b * MD + t * 32;
#pragma unroll
    for (int i = 0; i < 32; ++i) atomicAdd(&o[i], oacc[i]);
}

extern "C" void kernel_launch(void* const* d_in, const int* in_sizes, int n_in,
                              void* d_out, int out_size, void* d_ws, size_t ws_size,
                              hipStream_t stream)
{
    const float* x   = (const float*)d_in[0];   // [16,256,128]
    const float* act = (const float*)d_in[1];   // [16,256]
    const float* W   = (const float*)d_in[2];   // [256,128,128,64]
    // d_in[3] = num_iter (==1), unused

    float* out      = (float*)d_out;
    float* out0     = out;                        // [16,128,64]  = 131072 elements
    float* next_act = out + 131072;               // [16,128]     = 2048
    float* qk_out   = out + 131072 + 2048;        // [16,256,128] = 524288

    // workspace: votes bf16 (64 MiB) | ncv_acc fp32 (512 KiB) | qk_scale (64 B)
    __hip_bfloat16* votes = (__hip_bfloat16*)d_ws;
    float* ncv_acc  = (float*)((char*)d_ws + (size_t)67108864);
    float* qk_scale = (float*)((char*)d_ws + (size_t)67108864 + 524288);

    hipMemsetAsync(ncv_acc, 0, (size_t)BB * MD * sizeof(float), stream);
    hipMemsetAsync(out0, 0, (size_t)BB * MD * sizeof(float), stream);

    pass1_votes<<<dim3(32, 32), 256, 0, stream>>>(x, W, votes, ncv_acc);
    pass2_act<<<16, 64, 0, stream>>>(act, next_act, qk_scale);
    pass3_route<<<dim3(16, 16), 256, 0, stream>>>(votes, ncv_acc, act, qk_scale, out0, qk_out);
}

// Round 3
// 375.049 us; speedup vs baseline: 1.3729x; 1.3729x over previous
//
#include <hip/hip_runtime.h>
#include <hip/hip_bf16.h>
#include <cstdint>

// CapsuleFC: B=16, N_IN=256, D_IN=128, N_OUT=128, D_OUT=64
// votes[b,n,m,d] = sum_a x[b,n,a] * W[n,a,m,d]        (W is 1 GiB fp32 -> HBM-bound)
// ncv[b,m,d]    = sum_n votes / N_OUT
// scores[b,n,m] = (1/8) * sum_d votes * ncv
// qk            = softmax_m(scores) * amean_b/(amean_b+1e-10)   (next_act const over m)
// out0[b,m,d]   = sum_n qk * act[b,n] * votes

#define BB 16
#define N_IN 256
#define D_IN 128
#define N_OUT 128
#define D_OUT 64
#define MD (N_OUT * D_OUT) /* 8192 */

// ---------------- Pass 0: transpose x -> xT[n][a][b] (b contiguous) ----------------
__global__ __launch_bounds__(256) void pass0_xT(
    const float* __restrict__ x, float* __restrict__ xT)
{
    const int idx = blockIdx.x * 256 + threadIdx.x;  // 524288 total
    const int b = idx & 15;
    const int a = (idx >> 4) & 127;
    const int n = idx >> 11;
    xT[idx] = x[((size_t)b * N_IN + n) * D_IN + a];  // write coalesced
}

// ---------------- Pass 1: votes (bf16x2) + ncv partial sums ----------------
// grid (16 j-chunks of 512, 64 n-groups of 4), block 256. Thread owns j = chunk*512+t*2 (2 cols).
// x values are block-uniform -> scalar loads from xT; NO LDS in the hot loop.
__global__ __launch_bounds__(256) void pass1_votes(
    const float* __restrict__ xT, const float* __restrict__ W,
    uint32_t* __restrict__ votes2, float* __restrict__ ncv_acc)
{
    const int t = threadIdx.x;
    const int chunk = blockIdx.x;   // 0..15
    const int ng = blockIdx.y;      // 0..63
    const int j = chunk * 512 + t * 2;

    float ncvloc[BB][2];
#pragma unroll
    for (int b = 0; b < BB; ++b) { ncvloc[b][0] = 0.f; ncvloc[b][1] = 0.f; }

    for (int ni = 0; ni < 4; ++ni) {
        const int n = ng * 4 + ni;
        const float2* __restrict__ Wp =
            reinterpret_cast<const float2*>(W + (size_t)n * D_IN * MD + j);
        const float4* __restrict__ xp =
            reinterpret_cast<const float4*>(xT + (size_t)n * D_IN * BB);

        float acc[BB][2];
#pragma unroll
        for (int b = 0; b < BB; ++b) { acc[b][0] = 0.f; acc[b][1] = 0.f; }

#pragma unroll 2
        for (int a = 0; a < D_IN; ++a) {
            const float2 w = Wp[(size_t)a * (MD / 2)];   // 512 B/wave, coalesced
            float xv[16];
#pragma unroll
            for (int q = 0; q < 4; ++q) {                // uniform address -> s_load
                const float4 f = xp[a * 4 + q];
                xv[4 * q + 0] = f.x; xv[4 * q + 1] = f.y;
                xv[4 * q + 2] = f.z; xv[4 * q + 3] = f.w;
            }
#pragma unroll
            for (int b = 0; b < BB; ++b) {
                acc[b][0] = fmaf(xv[b], w.x, acc[b][0]);
                acc[b][1] = fmaf(xv[b], w.y, acc[b][1]);
            }
        }

#pragma unroll
        for (int b = 0; b < BB; ++b) {
            union { __hip_bfloat16 h[2]; uint32_t u; } pk;
            pk.h[0] = __float2bfloat16(acc[b][0]);
            pk.h[1] = __float2bfloat16(acc[b][1]);
            votes2[(((size_t)b * N_IN + n) * MD + j) >> 1] = pk.u;
            ncvloc[b][0] += acc[b][0];
            ncvloc[b][1] += acc[b][1];
        }
    }
#pragma unroll
    for (int b = 0; b < BB; ++b) {
        atomicAdd(&ncv_acc[b * MD + j],     ncvloc[b][0]);
        atomicAdd(&ncv_acc[b * MD + j + 1], ncvloc[b][1]);
    }
}

// ---------------- Pass 2: next_act + qk scale ----------------
__global__ __launch_bounds__(64) void pass2_act(
    const float* __restrict__ act, float* __restrict__ next_act_out,
    float* __restrict__ qk_scale)
{
    const int b = blockIdx.x;  // 16
    const int t = threadIdx.x; // 64
    float v = act[b * N_IN + t] + act[b * N_IN + 64 + t] +
              act[b * N_IN + 128 + t] + act[b * N_IN + 192 + t];
#pragma unroll
    for (int off = 32; off; off >>= 1) v += __shfl_down(v, off);
    v = __shfl(v, 0);
    const float amean = v * (1.f / 256.f);
    if (t == 0) qk_scale[b] = amean / (amean + 1e-10f);
    for (int m = t; m < N_OUT; m += 64) next_act_out[b * N_OUT + m] = amean;
}

// ---------------- Pass 3: scores -> softmax -> qk -> weighted reduce ----------------
// grid (16 b, 16 n-chunks of 16), block 256. thread t owns m=t>>1, d-half=t&1 (32 d's).
// No max-subtraction: |scores| << 88 so exp cannot overflow; softmax shift-invariant.
__global__ __launch_bounds__(256) void pass3_route(
    const __hip_bfloat16* __restrict__ votes, const float* __restrict__ ncv_acc,
    const float* __restrict__ act, const float* __restrict__ qk_scale,
    float* __restrict__ out0, float* __restrict__ qk_out)
{
    __shared__ float red[4];
    const int t = threadIdx.x;
    const int b = blockIdx.x;
    const int nc = blockIdx.y;
    const int m = t >> 1;
    const int half = t & 1;

    float nv[32], oacc[32];
    {
        const float4* np4 = reinterpret_cast<const float4*>(ncv_acc + (size_t)b * MD + t * 32);
#pragma unroll
        for (int q = 0; q < 8; ++q) {
            float4 f = np4[q];
            nv[4 * q + 0] = f.x; nv[4 * q + 1] = f.y;
            nv[4 * q + 2] = f.z; nv[4 * q + 3] = f.w;
        }
#pragma unroll
        for (int i = 0; i < 32; ++i) { nv[i] *= (1.f / (float)N_OUT); oacc[i] = 0.f; }
    }
    const float qs = qk_scale[b];

    const uint4* vbase = reinterpret_cast<const uint4*>(
        votes + (size_t)b * ((size_t)N_IN * MD) + (size_t)(nc * 16) * MD + t * 32);
    const size_t nstride = MD / 8;  // uint4 units per n

    uint4 buf[4];
#pragma unroll
    for (int q = 0; q < 4; ++q) buf[q] = vbase[q];

    for (int ni = 0; ni < 16; ++ni) {
        const int n = nc * 16 + ni;
        float vv[32];
#pragma unroll
        for (int q = 0; q < 4; ++q) {
            const uint32_t ww[4] = {buf[q].x, buf[q].y, buf[q].z, buf[q].w};
#pragma unroll
            for (int k = 0; k < 4; ++k) {
                vv[8 * q + 2 * k]     = __uint_as_float(ww[k] << 16);
                vv[8 * q + 2 * k + 1] = __uint_as_float(ww[k] & 0xffff0000u);
            }
        }
        if (ni < 15) {  // prefetch next n while we reduce
            const uint4* vn = vbase + (size_t)(ni + 1) * nstride;
#pragma unroll
            for (int q = 0; q < 4; ++q) buf[q] = vn[q];
        }

        // score for (b,n,m): dot over 64 d split across thread pair
        float sp = 0.f;
#pragma unroll
        for (int i = 0; i < 32; ++i) sp = fmaf(vv[i], nv[i], sp);
        sp += __shfl_xor(sp, 1);
        sp *= 0.125f; // 1/sqrt(D_OUT)

        const float p = __expf(sp);
        float s = p;
#pragma unroll
        for (int off = 32; off; off >>= 1) s += __shfl_xor(s, off);
        if ((t & 63) == 0) red[t >> 6] = s;
        __syncthreads();
        const float ssum = (red[0] + red[1] + red[2] + red[3]) * 0.5f; // each m counted twice
        __syncthreads();

        const float qk = (p / ssum) * qs;
        if (half == 0) qk_out[((size_t)(b * N_IN + n) << 7) + m] = qk;

        const float c = qk * act[b * N_IN + n];
#pragma unroll
        for (int i = 0; i < 32; ++i) oacc[i] = fmaf(c, vv[i], oacc[i]);
    }

    float* o = out0 + (size_t)b * MD + t * 32;
#pragma unroll
    for (int i = 0; i < 32; ++i) atomicAdd(&o[i], oacc[i]);
}

extern "C" void kernel_launch(void* const* d_in, const int* in_sizes, int n_in,
                              void* d_out, int out_size, void* d_ws, size_t ws_size,
                              hipStream_t stream)
{
    const float* x   = (const float*)d_in[0];   // [16,256,128]
    const float* act = (const float*)d_in[1];   // [16,256]
    const float* W   = (const float*)d_in[2];   // [256,128,128,64]
    // d_in[3] = num_iter (==1), unused

    float* out      = (float*)d_out;
    float* out0     = out;                        // [16,128,64]  = 131072 elements
    float* next_act = out + 131072;               // [16,128]     = 2048
    float* qk_out   = out + 131072 + 2048;        // [16,256,128] = 524288

    // workspace: votes bf16 (64 MiB) | ncv_acc fp32 (512 KiB) | qk_scale | xT (2 MiB)
    __hip_bfloat16* votes = (__hip_bfloat16*)d_ws;
    float* ncv_acc  = (float*)((char*)d_ws + (size_t)67108864);
    float* qk_scale = (float*)((char*)d_ws + (size_t)67108864 + 524288);
    float* xT       = (float*)((char*)d_ws + (size_t)67108864 + 524288 + 4096);

    hipMemsetAsync(ncv_acc, 0, (size_t)BB * MD * sizeof(float), stream);
    hipMemsetAsync(out0, 0, (size_t)BB * MD * sizeof(float), stream);

    pass0_xT<<<2048, 256, 0, stream>>>(x, xT);
    pass1_votes<<<dim3(16, 64), 256, 0, stream>>>(xT, W, (uint32_t*)votes, ncv_acc);
    pass2_act<<<16, 64, 0, stream>>>(act, next_act, qk_scale);
    pass3_route<<<dim3(16, 16), 256, 0, stream>>>(votes, ncv_acc, act, qk_scale, out0, qk_out);
}

// Round 4
// 368.803 us; speedup vs baseline: 1.3962x; 1.0169x over previous
//
#include <hip/hip_runtime.h>
#include <hip/hip_bf16.h>
#include <cstdint>

// CapsuleFC: B=16, N_IN=256, D_IN=128, N_OUT=128, D_OUT=64
// votes[b,n,m,d] = sum_a x[b,n,a] * W[n,a,m,d]        (W is 1 GiB fp32 -> HBM-bound)
// ncv[b,m,d]    = (sum_n votes) / N_OUT
// scores[b,n,m] = (1/8) * sum_d votes * ncv
// qk            = softmax_m(scores) * amean_b/(amean_b+1e-10)   (next_act const over m)
// out0[b,m,d]   = sum_n qk * act[b,n] * votes

#define BB 16
#define N_IN 256
#define D_IN 128
#define N_OUT 128
#define D_OUT 64
#define MD (N_OUT * D_OUT) /* 8192 */
#define NPB 4               /* n per block in pass1 */

// ---------------- Pass 0: transpose x -> xT[n][a][b] (b contiguous) ----------------
__global__ __launch_bounds__(256) void pass0_xT(
    const float* __restrict__ x, float* __restrict__ xT)
{
    const int idx = blockIdx.x * 256 + threadIdx.x;  // 524288 total
    const int b = idx & 15;
    const int a = (idx >> 4) & 127;
    const int n = idx >> 11;
    xT[idx] = x[((size_t)b * N_IN + n) * D_IN + a];  // write coalesced
}

// ---------------- Pass 1: votes (bf16x2), x staged in LDS ----------------
// grid (16 j-chunks of 512, 64 n-groups of 4), block 256. Thread owns j=chunk*512+t*2.
// x reads come from LDS (lgkmcnt) so the vmcnt stream is PURE W loads -> deep pipeline.
__global__ __launch_bounds__(256, 4) void pass1_votes(
    const float* __restrict__ xT, const float* __restrict__ W,
    uint32_t* __restrict__ votes2)
{
    __shared__ float xs[NPB * D_IN * BB]; // 32 KB
    const int t = threadIdx.x;
    const int chunk = blockIdx.x;   // 0..15
    const int ng = blockIdx.y;      // 0..63
    const int j = chunk * 512 + t * 2;

    // stage x[ng*4 .. ng*4+3] : 8192 floats, 32 per thread, coalesced float4
    {
        const float4* src = reinterpret_cast<const float4*>(xT + ((size_t)ng * NPB << 11));
        float4* dst = reinterpret_cast<float4*>(xs);
#pragma unroll
        for (int r = 0; r < 8; ++r) dst[r * 256 + t] = src[r * 256 + t];
    }
    __syncthreads();

    for (int ni = 0; ni < NPB; ++ni) {
        const int n = ng * NPB + ni;
        const float2* __restrict__ Wp =
            reinterpret_cast<const float2*>(W + (size_t)n * D_IN * MD + j);

        float acc[BB][2];
#pragma unroll
        for (int b = 0; b < BB; ++b) { acc[b][0] = 0.f; acc[b][1] = 0.f; }

#pragma unroll 4
        for (int a = 0; a < D_IN; ++a) {
            const float2 w = Wp[(size_t)a * (MD / 2)];   // 512 B/wave, coalesced
            const float* xa = xs + (ni * D_IN + a) * BB; // uniform addr -> LDS broadcast
            float xv[BB];
#pragma unroll
            for (int b = 0; b < BB; ++b) xv[b] = xa[b];
#pragma unroll
            for (int b = 0; b < BB; ++b) {
                acc[b][0] = fmaf(xv[b], w.x, acc[b][0]);
                acc[b][1] = fmaf(xv[b], w.y, acc[b][1]);
            }
        }

#pragma unroll
        for (int b = 0; b < BB; ++b) {
            union { __hip_bfloat16 h[2]; uint32_t u; } pk;
            pk.h[0] = __float2bfloat16(acc[b][0]);
            pk.h[1] = __float2bfloat16(acc[b][1]);
            votes2[(((size_t)b * N_IN + n) * MD + j) >> 1] = pk.u;
        }
    }
}

// ---------------- Pass ncv: ncv_acc[b][j] = sum_n votes[b][n][j] (fp32) ----------------
// grid (16 jc, 16 b), block 128. thread owns 4 consecutive bf16 (one uint2 per n).
__global__ __launch_bounds__(128) void pass_ncv(
    const uint32_t* __restrict__ votes2, float* __restrict__ ncv_acc)
{
    const int t = threadIdx.x;
    const int jc = blockIdx.x;
    const int b = blockIdx.y;
    const int j = jc * 512 + t * 4;

    const uint2* vp = reinterpret_cast<const uint2*>(votes2) +
                      (((size_t)b * N_IN * MD + j) >> 2);
    float s0 = 0.f, s1 = 0.f, s2 = 0.f, s3 = 0.f;
#pragma unroll 8
    for (int n = 0; n < N_IN; ++n) {
        const uint2 u = vp[(size_t)n * (MD / 4)];
        s0 += __uint_as_float(u.x << 16);
        s1 += __uint_as_float(u.x & 0xffff0000u);
        s2 += __uint_as_float(u.y << 16);
        s3 += __uint_as_float(u.y & 0xffff0000u);
    }
    float4 o; o.x = s0; o.y = s1; o.z = s2; o.w = s3;
    *reinterpret_cast<float4*>(ncv_acc + (size_t)b * MD + j) = o;
}

// ---------------- Pass 2: next_act + qk scale ----------------
__global__ __launch_bounds__(64) void pass2_act(
    const float* __restrict__ act, float* __restrict__ next_act_out,
    float* __restrict__ qk_scale)
{
    const int b = blockIdx.x;  // 16
    const int t = threadIdx.x; // 64
    float v = act[b * N_IN + t] + act[b * N_IN + 64 + t] +
              act[b * N_IN + 128 + t] + act[b * N_IN + 192 + t];
#pragma unroll
    for (int off = 32; off; off >>= 1) v += __shfl_down(v, off);
    v = __shfl(v, 0);
    const float amean = v * (1.f / 256.f);
    if (t == 0) qk_scale[b] = amean / (amean + 1e-10f);
    for (int m = t; m < N_OUT; m += 64) next_act_out[b * N_OUT + m] = amean;
}

// ---------------- Pass 3: scores -> softmax -> qk -> weighted reduce ----------------
// grid (16 b, 16 n-chunks of 16), block 256. thread t owns m=t>>1, d-half=t&1 (32 d's).
// No max-subtraction: |scores| << 88 so exp cannot overflow; softmax shift-invariant.
__global__ __launch_bounds__(256) void pass3_route(
    const __hip_bfloat16* __restrict__ votes, const float* __restrict__ ncv_acc,
    const float* __restrict__ act, const float* __restrict__ qk_scale,
    float* __restrict__ out0, float* __restrict__ qk_out)
{
    __shared__ float red[4];
    const int t = threadIdx.x;
    const int b = blockIdx.x;
    const int nc = blockIdx.y;
    const int m = t >> 1;
    const int half = t & 1;

    float nv[32], oacc[32];
    {
        const float4* np4 = reinterpret_cast<const float4*>(ncv_acc + (size_t)b * MD + t * 32);
#pragma unroll
        for (int q = 0; q < 8; ++q) {
            float4 f = np4[q];
            nv[4 * q + 0] = f.x; nv[4 * q + 1] = f.y;
            nv[4 * q + 2] = f.z; nv[4 * q + 3] = f.w;
        }
#pragma unroll
        for (int i = 0; i < 32; ++i) { nv[i] *= (1.f / (float)N_OUT); oacc[i] = 0.f; }
    }
    const float qs = qk_scale[b];

    const uint4* vbase = reinterpret_cast<const uint4*>(
        votes + (size_t)b * ((size_t)N_IN * MD) + (size_t)(nc * 16) * MD + t * 32);
    const size_t nstride = MD / 8;  // uint4 units per n

    uint4 buf[4];
#pragma unroll
    for (int q = 0; q < 4; ++q) buf[q] = vbase[q];

    for (int ni = 0; ni < 16; ++ni) {
        const int n = nc * 16 + ni;
        float vv[32];
#pragma unroll
        for (int q = 0; q < 4; ++q) {
            const uint32_t ww[4] = {buf[q].x, buf[q].y, buf[q].z, buf[q].w};
#pragma unroll
            for (int k = 0; k < 4; ++k) {
                vv[8 * q + 2 * k]     = __uint_as_float(ww[k] << 16);
                vv[8 * q + 2 * k + 1] = __uint_as_float(ww[k] & 0xffff0000u);
            }
        }
        if (ni < 15) {  // prefetch next n while we reduce
            const uint4* vn = vbase + (size_t)(ni + 1) * nstride;
#pragma unroll
            for (int q = 0; q < 4; ++q) buf[q] = vn[q];
        }

        // score dot over this thread's 32 d: 4 parallel chains to cut latency
        float p0 = 0.f, p1 = 0.f, p2 = 0.f, p3 = 0.f;
#pragma unroll
        for (int i = 0; i < 8; ++i) {
            p0 = fmaf(vv[4 * i + 0], nv[4 * i + 0], p0);
            p1 = fmaf(vv[4 * i + 1], nv[4 * i + 1], p1);
            p2 = fmaf(vv[4 * i + 2], nv[4 * i + 2], p2);
            p3 = fmaf(vv[4 * i + 3], nv[4 * i + 3], p3);
        }
        float sp = (p0 + p1) + (p2 + p3);
        sp += __shfl_xor(sp, 1);
        sp *= 0.125f; // 1/sqrt(D_OUT)

        const float p = __expf(sp);
        float s = p;
#pragma unroll
        for (int off = 32; off; off >>= 1) s += __shfl_xor(s, off);
        if ((t & 63) == 0) red[t >> 6] = s;
        __syncthreads();
        const float ssum = (red[0] + red[1] + red[2] + red[3]) * 0.5f; // each m counted twice
        __syncthreads();

        const float qk = (p / ssum) * qs;
        if (half == 0) qk_out[((size_t)(b * N_IN + n) << 7) + m] = qk;

        const float c = qk * act[b * N_IN + n];
#pragma unroll
        for (int i = 0; i < 32; ++i) oacc[i] = fmaf(c, vv[i], oacc[i]);
    }

    float* o = out0 + (size_t)b * MD + t * 32;
#pragma unroll
    for (int i = 0; i < 32; ++i) atomicAdd(&o[i], oacc[i]);
}

extern "C" void kernel_launch(void* const* d_in, const int* in_sizes, int n_in,
                              void* d_out, int out_size, void* d_ws, size_t ws_size,
                              hipStream_t stream)
{
    const float* x   = (const float*)d_in[0];   // [16,256,128]
    const float* act = (const float*)d_in[1];   // [16,256]
    const float* W   = (const float*)d_in[2];   // [256,128,128,64]
    // d_in[3] = num_iter (==1), unused

    float* out      = (float*)d_out;
    float* out0     = out;                        // [16,128,64]  = 131072 elements
    float* next_act = out + 131072;               // [16,128]     = 2048
    float* qk_out   = out + 131072 + 2048;        // [16,256,128] = 524288

    // workspace: votes bf16 (64 MiB) | ncv_acc fp32 (512 KiB) | qk_scale | xT (2 MiB)
    __hip_bfloat16* votes = (__hip_bfloat16*)d_ws;
    float* ncv_acc  = (float*)((char*)d_ws + (size_t)67108864);
    float* qk_scale = (float*)((char*)d_ws + (size_t)67108864 + 524288);
    float* xT       = (float*)((char*)d_ws + (size_t)67108864 + 524288 + 4096);

    hipMemsetAsync(out0, 0, (size_t)BB * MD * sizeof(float), stream);

    pass0_xT<<<2048, 256, 0, stream>>>(x, xT);
    pass1_votes<<<dim3(16, 64), 256, 0, stream>>>(xT, W, (uint32_t*)votes);
    pass_ncv<<<dim3(16, 16), 128, 0, stream>>>((const uint32_t*)votes, ncv_acc);
    pass2_act<<<16, 64, 0, stream>>>(act, next_act, qk_scale);
    pass3_route<<<dim3(16, 16), 256, 0, stream>>>(votes, ncv_acc, act, qk_scale, out0, qk_out);
}

// Round 5
// 362.522 us; speedup vs baseline: 1.4204x; 1.0173x over previous
//
#include <hip/hip_runtime.h>
#include <hip/hip_bf16.h>
#include <cstdint>

// CapsuleFC: B=16, N_IN=256, D_IN=128, N_OUT=128, D_OUT=64
// votes[b,n,m,d] = sum_a x[b,n,a] * W[n,a,m,d]        (W is 1 GiB fp32 -> HBM-bound)
// ncv[b,m,d]    = (sum_n votes) / N_OUT
// scores[b,n,m] = (1/8) * sum_d votes * ncv
// qk            = softmax_m(scores) * amean_b/(amean_b+1e-10)   (next_act const over m)
// out0[b,m,d]   = sum_n qk * act[b,n] * votes

#define BB 16
#define N_IN 256
#define D_IN 128
#define N_OUT 128
#define D_OUT 64
#define MD (N_OUT * D_OUT) /* 8192 */
#define NPB 2               /* n per block in pass1 */

// ---------------- Pass 0: transpose x -> xT[n][a][b] (b contiguous) ----------------
__global__ __launch_bounds__(256) void pass0_xT(
    const float* __restrict__ x, float* __restrict__ xT)
{
    const int idx = blockIdx.x * 256 + threadIdx.x;  // 524288 total
    const int b = idx & 15;
    const int a = (idx >> 4) & 127;
    const int n = idx >> 11;
    xT[idx] = x[((size_t)b * N_IN + n) * D_IN + a];  // write coalesced
}

// ---------------- Pass 1: votes (bf16x4), x staged in LDS ----------------
// grid (8 j-chunks of 1024, 128 n-groups of 2), block 256. Thread owns j=chunk*1024+t*4.
// Key ratio: per 16 B of W (float4), only 4 ds_read_b128 + 64 FMAs.
__global__ __launch_bounds__(256, 2) void pass1_votes(
    const float* __restrict__ xT, const float* __restrict__ W,
    uint2* __restrict__ votes4)
{
    __shared__ float xs[NPB * D_IN * BB]; // 16 KB
    const int t = threadIdx.x;
    const int chunk = blockIdx.x;   // 0..7
    const int ng = blockIdx.y;      // 0..127
    const int j = chunk * 1024 + t * 4;

    // stage x[ng*2, ng*2+1] : 4096 floats, coalesced float4 (4 per thread)
    {
        const float4* src = reinterpret_cast<const float4*>(xT + ((size_t)ng * NPB << 11));
        float4* dst = reinterpret_cast<float4*>(xs);
#pragma unroll
        for (int r = 0; r < 4; ++r) dst[r * 256 + t] = src[r * 256 + t];
    }
    __syncthreads();

    for (int ni = 0; ni < NPB; ++ni) {
        const int n = ng * NPB + ni;
        const float4* __restrict__ Wp =
            reinterpret_cast<const float4*>(W + (size_t)n * D_IN * MD + j);

        float acc[BB][4];
#pragma unroll
        for (int b = 0; b < BB; ++b) {
            acc[b][0] = 0.f; acc[b][1] = 0.f; acc[b][2] = 0.f; acc[b][3] = 0.f;
        }

#pragma unroll 4
        for (int a = 0; a < D_IN; ++a) {
            const float4 w = Wp[(size_t)a * (MD / 4)];   // 1 KB/wave, coalesced
            const float4* xa = reinterpret_cast<const float4*>(xs + (ni * D_IN + a) * BB);
            const float4 x0 = xa[0], x1 = xa[1], x2 = xa[2], x3 = xa[3]; // ds_read_b128 x4
            const float xv[BB] = {x0.x, x0.y, x0.z, x0.w, x1.x, x1.y, x1.z, x1.w,
                                  x2.x, x2.y, x2.z, x2.w, x3.x, x3.y, x3.z, x3.w};
#pragma unroll
            for (int b = 0; b < BB; ++b) {
                acc[b][0] = fmaf(xv[b], w.x, acc[b][0]);
                acc[b][1] = fmaf(xv[b], w.y, acc[b][1]);
                acc[b][2] = fmaf(xv[b], w.z, acc[b][2]);
                acc[b][3] = fmaf(xv[b], w.w, acc[b][3]);
            }
        }

#pragma unroll
        for (int b = 0; b < BB; ++b) {
            union { __hip_bfloat16 h[4]; uint2 u; } pk;
            pk.h[0] = __float2bfloat16(acc[b][0]);
            pk.h[1] = __float2bfloat16(acc[b][1]);
            pk.h[2] = __float2bfloat16(acc[b][2]);
            pk.h[3] = __float2bfloat16(acc[b][3]);
            votes4[(((size_t)b * N_IN + n) * MD + j) >> 2] = pk.u;
        }
    }
}

// ---------------- Pass ncv: ncv_acc[b][j] = sum_n votes[b][n][j] (fp32) ----------------
// grid (16 jc, 16 b), block 128. thread owns 4 consecutive bf16 (one uint2 per n).
__global__ __launch_bounds__(128) void pass_ncv(
    const uint32_t* __restrict__ votes2, float* __restrict__ ncv_acc)
{
    const int t = threadIdx.x;
    const int jc = blockIdx.x;
    const int b = blockIdx.y;
    const int j = jc * 512 + t * 4;

    const uint2* vp = reinterpret_cast<const uint2*>(votes2) +
                      (((size_t)b * N_IN * MD + j) >> 2);
    float s0 = 0.f, s1 = 0.f, s2 = 0.f, s3 = 0.f;
#pragma unroll 8
    for (int n = 0; n < N_IN; ++n) {
        const uint2 u = vp[(size_t)n * (MD / 4)];
        s0 += __uint_as_float(u.x << 16);
        s1 += __uint_as_float(u.x & 0xffff0000u);
        s2 += __uint_as_float(u.y << 16);
        s3 += __uint_as_float(u.y & 0xffff0000u);
    }
    float4 o; o.x = s0; o.y = s1; o.z = s2; o.w = s3;
    *reinterpret_cast<float4*>(ncv_acc + (size_t)b * MD + j) = o;
}

// ---------------- Pass 2: next_act + qk scale ----------------
__global__ __launch_bounds__(64) void pass2_act(
    const float* __restrict__ act, float* __restrict__ next_act_out,
    float* __restrict__ qk_scale)
{
    const int b = blockIdx.x;  // 16
    const int t = threadIdx.x; // 64
    float v = act[b * N_IN + t] + act[b * N_IN + 64 + t] +
              act[b * N_IN + 128 + t] + act[b * N_IN + 192 + t];
#pragma unroll
    for (int off = 32; off; off >>= 1) v += __shfl_down(v, off);
    v = __shfl(v, 0);
    const float amean = v * (1.f / 256.f);
    if (t == 0) qk_scale[b] = amean / (amean + 1e-10f);
    for (int m = t; m < N_OUT; m += 64) next_act_out[b * N_OUT + m] = amean;
}

// ---------------- Pass 3: scores -> softmax -> qk -> weighted reduce ----------------
// grid (16 b, 16 n-chunks of 16), block 256. thread t owns m=t>>1, d-half=t&1 (32 d's).
// No max-subtraction: |scores| << 88 so exp cannot overflow; softmax shift-invariant.
__global__ __launch_bounds__(256) void pass3_route(
    const __hip_bfloat16* __restrict__ votes, const float* __restrict__ ncv_acc,
    const float* __restrict__ act, const float* __restrict__ qk_scale,
    float* __restrict__ out0, float* __restrict__ qk_out)
{
    __shared__ float red[4];
    const int t = threadIdx.x;
    const int b = blockIdx.x;
    const int nc = blockIdx.y;
    const int m = t >> 1;
    const int half = t & 1;

    float nv[32], oacc[32];
    {
        const float4* np4 = reinterpret_cast<const float4*>(ncv_acc + (size_t)b * MD + t * 32);
#pragma unroll
        for (int q = 0; q < 8; ++q) {
            float4 f = np4[q];
            nv[4 * q + 0] = f.x; nv[4 * q + 1] = f.y;
            nv[4 * q + 2] = f.z; nv[4 * q + 3] = f.w;
        }
#pragma unroll
        for (int i = 0; i < 32; ++i) { nv[i] *= (1.f / (float)N_OUT); oacc[i] = 0.f; }
    }
    const float qs = qk_scale[b];

    const uint4* vbase = reinterpret_cast<const uint4*>(
        votes + (size_t)b * ((size_t)N_IN * MD) + (size_t)(nc * 16) * MD + t * 32);
    const size_t nstride = MD / 8;  // uint4 units per n

    uint4 buf[4];
#pragma unroll
    for (int q = 0; q < 4; ++q) buf[q] = vbase[q];

    for (int ni = 0; ni < 16; ++ni) {
        const int n = nc * 16 + ni;
        float vv[32];
#pragma unroll
        for (int q = 0; q < 4; ++q) {
            const uint32_t ww[4] = {buf[q].x, buf[q].y, buf[q].z, buf[q].w};
#pragma unroll
            for (int k = 0; k < 4; ++k) {
                vv[8 * q + 2 * k]     = __uint_as_float(ww[k] << 16);
                vv[8 * q + 2 * k + 1] = __uint_as_float(ww[k] & 0xffff0000u);
            }
        }
        if (ni < 15) {  // prefetch next n while we reduce
            const uint4* vn = vbase + (size_t)(ni + 1) * nstride;
#pragma unroll
            for (int q = 0; q < 4; ++q) buf[q] = vn[q];
        }

        // score dot over this thread's 32 d: 4 parallel chains to cut latency
        float p0 = 0.f, p1 = 0.f, p2 = 0.f, p3 = 0.f;
#pragma unroll
        for (int i = 0; i < 8; ++i) {
            p0 = fmaf(vv[4 * i + 0], nv[4 * i + 0], p0);
            p1 = fmaf(vv[4 * i + 1], nv[4 * i + 1], p1);
            p2 = fmaf(vv[4 * i + 2], nv[4 * i + 2], p2);
            p3 = fmaf(vv[4 * i + 3], nv[4 * i + 3], p3);
        }
        float sp = (p0 + p1) + (p2 + p3);
        sp += __shfl_xor(sp, 1);
        sp *= 0.125f; // 1/sqrt(D_OUT)

        const float p = __expf(sp);
        float s = p;
#pragma unroll
        for (int off = 32; off; off >>= 1) s += __shfl_xor(s, off);
        if ((t & 63) == 0) red[t >> 6] = s;
        __syncthreads();
        const float ssum = (red[0] + red[1] + red[2] + red[3]) * 0.5f; // each m counted twice
        __syncthreads();

        const float qk = (p / ssum) * qs;
        if (half == 0) qk_out[((size_t)(b * N_IN + n) << 7) + m] = qk;

        const float c = qk * act[b * N_IN + n];
#pragma unroll
        for (int i = 0; i < 32; ++i) oacc[i] = fmaf(c, vv[i], oacc[i]);
    }

    float* o = out0 + (size_t)b * MD + t * 32;
#pragma unroll
    for (int i = 0; i < 32; ++i) atomicAdd(&o[i], oacc[i]);
}

extern "C" void kernel_launch(void* const* d_in, const int* in_sizes, int n_in,
                              void* d_out, int out_size, void* d_ws, size_t ws_size,
                              hipStream_t stream)
{
    const float* x   = (const float*)d_in[0];   // [16,256,128]
    const float* act = (const float*)d_in[1];   // [16,256]
    const float* W   = (const float*)d_in[2];   // [256,128,128,64]
    // d_in[3] = num_iter (==1), unused

    float* out      = (float*)d_out;
    float* out0     = out;                        // [16,128,64]  = 131072 elements
    float* next_act = out + 131072;               // [16,128]     = 2048
    float* qk_out   = out + 131072 + 2048;        // [16,256,128] = 524288

    // workspace: votes bf16 (64 MiB) | ncv_acc fp32 (512 KiB) | qk_scale | xT (2 MiB)
    __hip_bfloat16* votes = (__hip_bfloat16*)d_ws;
    float* ncv_acc  = (float*)((char*)d_ws + (size_t)67108864);
    float* qk_scale = (float*)((char*)d_ws + (size_t)67108864 + 524288);
    float* xT       = (float*)((char*)d_ws + (size_t)67108864 + 524288 + 4096);

    hipMemsetAsync(out0, 0, (size_t)BB * MD * sizeof(float), stream);

    pass0_xT<<<2048, 256, 0, stream>>>(x, xT);
    pass1_votes<<<dim3(8, 128), 256, 0, stream>>>(xT, W, (uint2*)votes);
    pass_ncv<<<dim3(16, 16), 128, 0, stream>>>((const uint32_t*)votes, ncv_acc);
    pass2_act<<<16, 64, 0, stream>>>(act, next_act, qk_scale);
    pass3_route<<<dim3(16, 16), 256, 0, stream>>>(votes, ncv_acc, act, qk_scale, out0, qk_out);
}

// Round 6
// 272.049 us; speedup vs baseline: 1.8927x; 1.3326x over previous
//
#include <hip/hip_runtime.h>
#include <hip/hip_bf16.h>
#include <cstdint>

// CapsuleFC: B=16, N_IN=256, D_IN=128, N_OUT=128, D_OUT=64
// votes[b,n,m,d] = sum_a x[b,n,a] * W[n,a,m,d]        (W is 1 GiB fp32 -> HBM-bound)
// ncv[b,m,d]    = (sum_n votes) / N_OUT
// scores[b,n,m] = (1/8) * sum_d votes * ncv
// qk            = softmax_m(scores) * amean_b/(amean_b+1e-10)   (next_act const over m)
// out0[b,m,d]   = sum_n qk * act[b,n] * votes

#define BB 16
#define N_IN 256
#define D_IN 128
#define N_OUT 128
#define D_OUT 64
#define MD (N_OUT * D_OUT) /* 8192 */
#define NPB 2               /* n per block in pass1 */
#define NCH 32              /* n-chunks in pass3 (8 n each) */

// ---------------- Pass 0: transpose x -> xT[n][a][b] (b contiguous) ----------------
__global__ __launch_bounds__(256) void pass0_xT(
    const float* __restrict__ x, float* __restrict__ xT)
{
    const int idx = blockIdx.x * 256 + threadIdx.x;  // 524288 total
    const int b = idx & 15;
    const int a = (idx >> 4) & 127;
    const int n = idx >> 11;
    xT[idx] = x[((size_t)b * N_IN + n) * D_IN + a];  // write coalesced
}

// ---------------- Pass 1: votes (bf16x4), x staged in LDS (UNCHANGED from R5) ---------
__global__ __launch_bounds__(256, 2) void pass1_votes(
    const float* __restrict__ xT, const float* __restrict__ W,
    uint2* __restrict__ votes4)
{
    __shared__ float xs[NPB * D_IN * BB]; // 16 KB
    const int t = threadIdx.x;
    const int chunk = blockIdx.x;   // 0..7
    const int ng = blockIdx.y;      // 0..127
    const int j = chunk * 1024 + t * 4;

    {
        const float4* src = reinterpret_cast<const float4*>(xT + ((size_t)ng * NPB << 11));
        float4* dst = reinterpret_cast<float4*>(xs);
#pragma unroll
        for (int r = 0; r < 4; ++r) dst[r * 256 + t] = src[r * 256 + t];
    }
    __syncthreads();

    for (int ni = 0; ni < NPB; ++ni) {
        const int n = ng * NPB + ni;
        const float4* __restrict__ Wp =
            reinterpret_cast<const float4*>(W + (size_t)n * D_IN * MD + j);

        float acc[BB][4];
#pragma unroll
        for (int b = 0; b < BB; ++b) {
            acc[b][0] = 0.f; acc[b][1] = 0.f; acc[b][2] = 0.f; acc[b][3] = 0.f;
        }

#pragma unroll 4
        for (int a = 0; a < D_IN; ++a) {
            const float4 w = Wp[(size_t)a * (MD / 4)];   // 1 KB/wave, coalesced
            const float4* xa = reinterpret_cast<const float4*>(xs + (ni * D_IN + a) * BB);
            const float4 x0 = xa[0], x1 = xa[1], x2 = xa[2], x3 = xa[3];
            const float xv[BB] = {x0.x, x0.y, x0.z, x0.w, x1.x, x1.y, x1.z, x1.w,
                                  x2.x, x2.y, x2.z, x2.w, x3.x, x3.y, x3.z, x3.w};
#pragma unroll
            for (int b = 0; b < BB; ++b) {
                acc[b][0] = fmaf(xv[b], w.x, acc[b][0]);
                acc[b][1] = fmaf(xv[b], w.y, acc[b][1]);
                acc[b][2] = fmaf(xv[b], w.z, acc[b][2]);
                acc[b][3] = fmaf(xv[b], w.w, acc[b][3]);
            }
        }

#pragma unroll
        for (int b = 0; b < BB; ++b) {
            union { __hip_bfloat16 h[4]; uint2 u; } pk;
            pk.h[0] = __float2bfloat16(acc[b][0]);
            pk.h[1] = __float2bfloat16(acc[b][1]);
            pk.h[2] = __float2bfloat16(acc[b][2]);
            pk.h[3] = __float2bfloat16(acc[b][3]);
            votes4[(((size_t)b * N_IN + n) * MD + j) >> 2] = pk.u;
        }
    }
}

// -------- Pass ncv-part: ncv_part[nh][b][j] = sum over 64 n of votes (fp32) --------
// grid (8 jc, 4 nh, 16 b), block 256 -> 512 blocks, 8 waves/CU, 64-iter chains.
__global__ __launch_bounds__(256) void pass_ncv_part(
    const uint32_t* __restrict__ votes2, float* __restrict__ ncv_part)
{
    const int t = threadIdx.x;
    const int jc = blockIdx.x;   // 0..7
    const int nh = blockIdx.y;   // 0..3
    const int b  = blockIdx.z;   // 0..15
    const int j = jc * 1024 + t * 4;

    const uint2* vp = reinterpret_cast<const uint2*>(votes2) +
                      ((((size_t)b * N_IN + (size_t)nh * 64) * MD + j) >> 2);
    float s0 = 0.f, s1 = 0.f, s2 = 0.f, s3 = 0.f;
#pragma unroll 8
    for (int n = 0; n < 64; ++n) {
        const uint2 u = vp[(size_t)n * (MD / 4)];
        s0 += __uint_as_float(u.x << 16);
        s1 += __uint_as_float(u.x & 0xffff0000u);
        s2 += __uint_as_float(u.y << 16);
        s3 += __uint_as_float(u.y & 0xffff0000u);
    }
    float4 o; o.x = s0; o.y = s1; o.z = s2; o.w = s3;
    *reinterpret_cast<float4*>(ncv_part + ((size_t)nh * BB + b) * MD + j) = o;
}

// ---------------- Pass 3: amean + scores -> softmax -> qk -> partial reduce ----------
// grid (16 b, 32 nc), block 256. thread t owns m=t>>1, half=t&1 (32 d's). 8 n per block.
// Writes non-atomic out_part[nc][b][j]; also next_act (nc==0) and qk.
__global__ __launch_bounds__(256) void pass3_route(
    const __hip_bfloat16* __restrict__ votes, const float* __restrict__ ncv_part,
    const float* __restrict__ act, float* __restrict__ out_part,
    float* __restrict__ next_act_out, float* __restrict__ qk_out)
{
    __shared__ float red[4];
    __shared__ float aw[4];
    const int t = threadIdx.x;
    const int b = blockIdx.x;
    const int nc = blockIdx.y;
    const int m = t >> 1;
    const int half = t & 1;

    // amean for this b (folded pass2)
    float av = act[b * N_IN + t];
#pragma unroll
    for (int off = 32; off; off >>= 1) av += __shfl_xor(av, off);
    if ((t & 63) == 0) aw[t >> 6] = av;
    __syncthreads();
    const float amean = (aw[0] + aw[1] + aw[2] + aw[3]) * (1.f / 256.f);
    const float qs = amean / (amean + 1e-10f);
    if (nc == 0 && half == 0) next_act_out[b * N_OUT + m] = amean;

    // nv = (sum of 4 ncv partials) / N_OUT ; oacc = 0
    float nv[32], oacc[32];
    {
        const float4* p0 = reinterpret_cast<const float4*>(ncv_part + ((size_t)0 * BB + b) * MD + t * 32);
        const float4* p1 = reinterpret_cast<const float4*>(ncv_part + ((size_t)1 * BB + b) * MD + t * 32);
        const float4* p2 = reinterpret_cast<const float4*>(ncv_part + ((size_t)2 * BB + b) * MD + t * 32);
        const float4* p3 = reinterpret_cast<const float4*>(ncv_part + ((size_t)3 * BB + b) * MD + t * 32);
#pragma unroll
        for (int q = 0; q < 8; ++q) {
            const float4 a0 = p0[q], a1 = p1[q], a2 = p2[q], a3 = p3[q];
            nv[4 * q + 0] = (a0.x + a1.x) + (a2.x + a3.x);
            nv[4 * q + 1] = (a0.y + a1.y) + (a2.y + a3.y);
            nv[4 * q + 2] = (a0.z + a1.z) + (a2.z + a3.z);
            nv[4 * q + 3] = (a0.w + a1.w) + (a2.w + a3.w);
        }
#pragma unroll
        for (int i = 0; i < 32; ++i) { nv[i] *= (1.f / (float)N_OUT); oacc[i] = 0.f; }
    }

    const uint4* vbase = reinterpret_cast<const uint4*>(
        votes + (size_t)b * ((size_t)N_IN * MD) + (size_t)(nc * 8) * MD + t * 32);
    const size_t nstride = MD / 8;  // uint4 units per n

    uint4 buf[4];
#pragma unroll
    for (int q = 0; q < 4; ++q) buf[q] = vbase[q];

    for (int ni = 0; ni < 8; ++ni) {
        const int n = nc * 8 + ni;
        float vv[32];
#pragma unroll
        for (int q = 0; q < 4; ++q) {
            const uint32_t ww[4] = {buf[q].x, buf[q].y, buf[q].z, buf[q].w};
#pragma unroll
            for (int k = 0; k < 4; ++k) {
                vv[8 * q + 2 * k]     = __uint_as_float(ww[k] << 16);
                vv[8 * q + 2 * k + 1] = __uint_as_float(ww[k] & 0xffff0000u);
            }
        }
        if (ni < 7) {  // prefetch next n while we reduce
            const uint4* vn = vbase + (size_t)(ni + 1) * nstride;
#pragma unroll
            for (int q = 0; q < 4; ++q) buf[q] = vn[q];
        }

        // score dot over this thread's 32 d: 4 parallel chains
        float p0 = 0.f, p1 = 0.f, p2 = 0.f, p3 = 0.f;
#pragma unroll
        for (int i = 0; i < 8; ++i) {
            p0 = fmaf(vv[4 * i + 0], nv[4 * i + 0], p0);
            p1 = fmaf(vv[4 * i + 1], nv[4 * i + 1], p1);
            p2 = fmaf(vv[4 * i + 2], nv[4 * i + 2], p2);
            p3 = fmaf(vv[4 * i + 3], nv[4 * i + 3], p3);
        }
        float sp = (p0 + p1) + (p2 + p3);
        sp += __shfl_xor(sp, 1);
        sp *= 0.125f; // 1/sqrt(D_OUT)

        const float p = __expf(sp);   // |scores| << 88, no max-shift needed
        float s = p;
#pragma unroll
        for (int off = 32; off; off >>= 1) s += __shfl_xor(s, off);
        if ((t & 63) == 0) red[t >> 6] = s;
        __syncthreads();
        const float ssum = (red[0] + red[1] + red[2] + red[3]) * 0.5f; // each m twice
        __syncthreads();

        const float qk = (p / ssum) * qs;
        if (half == 0) qk_out[((size_t)(b * N_IN + n) << 7) + m] = qk;

        const float c = qk * act[b * N_IN + n];
#pragma unroll
        for (int i = 0; i < 32; ++i) oacc[i] = fmaf(c, vv[i], oacc[i]);
    }

    float4* op = reinterpret_cast<float4*>(out_part + ((size_t)nc * BB + b) * MD + t * 32);
#pragma unroll
    for (int q = 0; q < 8; ++q) {
        float4 o; o.x = oacc[4 * q]; o.y = oacc[4 * q + 1];
        o.z = oacc[4 * q + 2]; o.w = oacc[4 * q + 3];
        op[q] = o;
    }
}

// ---------------- Combine: out0[b][j] = sum over 32 nc partials ----------------
__global__ __launch_bounds__(256) void combine_out0(
    const float* __restrict__ out_part, float* __restrict__ out0)
{
    const int idx = blockIdx.x * 256 + threadIdx.x;  // 32768 float4s
    const int b = idx >> 11;          // /2048
    const int v4 = idx & 2047;
    const float4* p = reinterpret_cast<const float4*>(out_part);
    float4 s = {0.f, 0.f, 0.f, 0.f};
#pragma unroll 8
    for (int nc = 0; nc < NCH; ++nc) {
        const float4 f = p[((size_t)nc * BB + b) * (MD / 4) + v4];
        s.x += f.x; s.y += f.y; s.z += f.z; s.w += f.w;
    }
    reinterpret_cast<float4*>(out0)[idx] = s;
}

extern "C" void kernel_launch(void* const* d_in, const int* in_sizes, int n_in,
                              void* d_out, int out_size, void* d_ws, size_t ws_size,
                              hipStream_t stream)
{
    const float* x   = (const float*)d_in[0];   // [16,256,128]
    const float* act = (const float*)d_in[1];   // [16,256]
    const float* W   = (const float*)d_in[2];   // [256,128,128,64]
    // d_in[3] = num_iter (==1), unused

    float* out      = (float*)d_out;
    float* out0     = out;                        // [16,128,64]  = 131072 elements
    float* next_act = out + 131072;               // [16,128]     = 2048
    float* qk_out   = out + 131072 + 2048;        // [16,256,128] = 524288

    // ws layout: votes bf16 64 MiB | ncv_part 2 MiB | out_part 16 MiB | xT 2 MiB
    __hip_bfloat16* votes = (__hip_bfloat16*)d_ws;
    float* ncv_part = (float*)((char*)d_ws + (size_t)67108864);
    float* out_part = (float*)((char*)d_ws + (size_t)67108864 + 2097152);
    float* xT       = (float*)((char*)d_ws + (size_t)67108864 + 2097152 + 16777216);

    pass0_xT<<<2048, 256, 0, stream>>>(x, xT);
    pass1_votes<<<dim3(8, 128), 256, 0, stream>>>(xT, W, (uint2*)votes);
    pass_ncv_part<<<dim3(8, 4, 16), 256, 0, stream>>>((const uint32_t*)votes, ncv_part);
    pass3_route<<<dim3(16, NCH), 256, 0, stream>>>(votes, ncv_part, act, out_part,
                                                   next_act, qk_out);
    combine_out0<<<128, 256, 0, stream>>>(out_part, out0);
}